// Round 3
// baseline (283.657 us; speedup 1.0000x reference)
//
#include <hip/hip_runtime.h>
#include <cstdint>

#define N_TOK   32768
#define DIM     1024
#define NEXP    64
#define TM      64
#define BK      32
#define KITERS  (DIM / BK)   // 32
#define NTHR    256
#define NBLK    (N_TOK / TM) // 512

typedef uint32_t __attribute__((address_space(3))) lds_u32_t;
typedef const uint32_t __attribute__((address_space(1))) glb_u32_t;

__device__ __forceinline__ void gload16(const float* g, float4* l) {
  // async global->LDS, 16 bytes per lane (dest = wave-uniform base + lane*16)
  __builtin_amdgcn_global_load_lds((glb_u32_t*)g, (lds_u32_t*)l, 16, 0, 0);
}

// XOR swizzle: row r, float4-slot s (0..7) stored at float4 position r*8 + (s ^ ((r>>2)&7)).
__device__ __forceinline__ int swz(int r, int s) { return (r << 3) + (s ^ ((r >> 2) & 7)); }

template<bool PART>
__launch_bounds__(NTHR, 4)
__global__ void router_kernel(const float* __restrict__ x,
                              const float* __restrict__ Wg,
                              float* __restrict__ out,
                              float* __restrict__ cnt_g,   // PART: [NBLK*64] partials; else [64] atomics
                              float* __restrict__ sp_g) {
  __shared__ float4 Xs4[2][TM * BK / 4];     // 2 x 8 KB
  __shared__ float4 Ws4[2][NEXP * BK / 4];   // 2 x 8 KB
  __shared__ float  colpart[4 * NEXP];       // per-wave expert prob partials
  __shared__ unsigned int cnt_s[NEXP];

  const int tid  = threadIdx.x;
  const int tx   = tid & 15;   // expert group: experts tx*4 .. tx*4+3
  const int ty   = tid >> 4;   // token group : tokens  ty*4 .. ty*4+3
  const int tok0 = blockIdx.x * TM;

  if (tid < NEXP) cnt_s[tid] = 0;

  // ---- staging coordinates (swizzled global source, linear LDS dest) ----
  int pA[2], pB[2];
  const float* srcA[2];
  const float* srcB[2];
#pragma unroll
  for (int q = 0; q < 2; ++q) {
    int p = q * 256 + tid;          // linear float4 position in A tile (512 total)
    pA[q] = p;
    int r = p >> 3, sc = p & 7;
    int s = sc ^ ((r >> 2) & 7);
    srcA[q] = x + (size_t)(tok0 + r) * DIM + s * 4;
  }
#pragma unroll
  for (int q = 0; q < 2; ++q) {
    int p = q * 256 + tid;          // 512 float4 in W tile
    pB[q] = p;
    int r = p >> 3, sc = p & 7;
    int s = sc ^ ((r >> 2) & 7);
    srcB[q] = Wg + (size_t)r * DIM + s * 4;
  }

  float acc[4][4];
#pragma unroll
  for (int i = 0; i < 4; ++i)
#pragma unroll
    for (int j = 0; j < 4; ++j) acc[i][j] = 0.f;

  // ---- prologue: stage buf 0 ----
#pragma unroll
  for (int q = 0; q < 2; ++q) { gload16(srcA[q], &Xs4[0][pA[q]]); srcA[q] += BK; }
#pragma unroll
  for (int q = 0; q < 2; ++q) { gload16(srcB[q], &Ws4[0][pB[q]]); srcB[q] += BK; }

  // ---- main K loop: double-buffer, counted vmcnt, raw barriers ----
  for (int it = 0; it < KITERS; ++it) {
    const int b = it & 1;
    if (it < KITERS - 1) {
#pragma unroll
      for (int q = 0; q < 2; ++q) { gload16(srcA[q], &Xs4[b ^ 1][pA[q]]); srcA[q] += BK; }
#pragma unroll
      for (int q = 0; q < 2; ++q) { gload16(srcB[q], &Ws4[b ^ 1][pB[q]]); srcB[q] += BK; }
      asm volatile("s_waitcnt vmcnt(4)" ::: "memory");  // 4 newest (next tile) stay in flight
    } else {
      asm volatile("s_waitcnt vmcnt(0)" ::: "memory");
    }
    __builtin_amdgcn_s_barrier();
    asm volatile("" ::: "memory");

#pragma unroll
    for (int dd = 0; dd < BK; dd += 4) {
      const int sidx = dd >> 2;
      float4 wv[4];
#pragma unroll
      for (int j = 0; j < 4; ++j) wv[j] = Ws4[b][swz(tx * 4 + j, sidx)];
#pragma unroll
      for (int i = 0; i < 4; ++i) {
        float4 xv = Xs4[b][swz(ty * 4 + i, sidx)];
#pragma unroll
        for (int j = 0; j < 4; ++j) {
          acc[i][j] = fmaf(xv.x, wv[j].x, acc[i][j]);
          acc[i][j] = fmaf(xv.y, wv[j].y, acc[i][j]);
          acc[i][j] = fmaf(xv.z, wv[j].z, acc[i][j]);
          acc[i][j] = fmaf(xv.w, wv[j].w, acc[i][j]);
        }
      }
    }
    asm volatile("" ::: "memory");
    __builtin_amdgcn_s_barrier();
    asm volatile("" ::: "memory");
  }

  // ---- epilogue: register softmax + top-2 over 16-lane groups ----
  float sp_loc[4] = {0.f, 0.f, 0.f, 0.f};

#pragma unroll
  for (int i = 0; i < 4; ++i) {
    // local top-2 among this lane's 4 experts
    float v1 = acc[i][0]; int e1 = tx * 4;
    float v2 = -3.4e38f;  int e2 = 0;
#pragma unroll
    for (int j = 1; j < 4; ++j) {
      float v = acc[i][j]; int e = tx * 4 + j;
      if (v > v1)      { v2 = v1; e2 = e1; v1 = v; e1 = e; }
      else if (v > v2) { v2 = v;  e2 = e; }
    }
    // butterfly merge across 16 lanes (tie-break: lower index)
#pragma unroll
    for (int m = 1; m <= 8; m <<= 1) {
      float b1 = __shfl_xor(v1, m), b2 = __shfl_xor(v2, m);
      int   f1 = __shfl_xor(e1, m), f2 = __shfl_xor(e2, m);
      bool bwin = (b1 > v1) || (b1 == v1 && f1 < e1);
      if (bwin) {
        bool keep = (v1 > b2) || (v1 == b2 && e1 < f2);
        v2 = keep ? v1 : b2; e2 = keep ? e1 : f2;
        v1 = b1; e1 = f1;
      } else {
        bool rep = (b1 > v2) || (b1 == v2 && f1 < e2);
        v2 = rep ? b1 : v2; e2 = rep ? f1 : e2;
      }
    }
    // stable softmax sum across the 16 lanes (all lanes have global max v1)
    float s = 0.f;
#pragma unroll
    for (int j = 0; j < 4; ++j) { float e = __expf(acc[i][j] - v1); acc[i][j] = e; s += e; }
#pragma unroll
    for (int m = 1; m <= 8; m <<= 1) s += __shfl_xor(s, m);
    float inv = 1.f / s;
#pragma unroll
    for (int j = 0; j < 4; ++j) sp_loc[j] += acc[i][j] * inv;

    if (tx == 0) {
      int g = tok0 + ty * 4 + i;
      float e2v = __expf(v2 - v1);
      float r = 1.f / (1.f + e2v);        // p1/(p1+p2)
      out[2 * g]     = r;
      out[2 * g + 1] = e2v * r;
      out[2 * N_TOK + 2 * g]     = (float)e1;
      out[2 * N_TOK + 2 * g + 1] = (float)e2;
      atomicAdd(&cnt_s[e1], 1u);
      atomicAdd(&cnt_s[e2], 1u);
    }
  }

  // ---- per-expert prob sums: reduce over ty ----
  // in-wave: sum the 4 ty-groups (lanes l, l+16, l+32, l+48)
#pragma unroll
  for (int j = 0; j < 4; ++j) {
    sp_loc[j] += __shfl_down(sp_loc[j], 32);
    sp_loc[j] += __shfl_down(sp_loc[j], 16);
  }
  const int lane = tid & 63;
  const int wv_i = tid >> 6;
  if (lane < 16) {
#pragma unroll
    for (int j = 0; j < 4; ++j) colpart[wv_i * 64 + tx * 4 + j] = sp_loc[j];
  }
  __syncthreads();

  if (tid < NEXP) {
    float t = colpart[tid] + colpart[64 + tid] + colpart[128 + tid] + colpart[192 + tid];
    if (PART) {
      sp_g[(size_t)blockIdx.x * NEXP + tid]  = t;
      cnt_g[(size_t)blockIdx.x * NEXP + tid] = (float)cnt_s[tid];
    } else {
      atomicAdd(&sp_g[tid], t);
      atomicAdd(&cnt_g[tid], (float)cnt_s[tid]);
    }
  }
}

__global__ void aux_kernel(const float* __restrict__ cnt_p,
                           const float* __restrict__ sp_p,
                           float* __restrict__ out, int nb) {
  __shared__ float redc[256], reds[256];
  const int t = threadIdx.x, e = t & 63, q = t >> 6;
  float sc = 0.f, ss = 0.f;
  for (int b = q; b < nb; b += 4) {
    sc += cnt_p[b * NEXP + e];
    ss += sp_p[b * NEXP + e];
  }
  redc[t] = sc; reds[t] = ss;
  __syncthreads();
  if (t < NEXP) {
    float C = redc[t] + redc[64 + t] + redc[128 + t] + redc[192 + t];
    float S = reds[t] + reds[64 + t] + reds[128 + t] + reds[192 + t];
    float v = C * S;
#pragma unroll
    for (int off = 32; off; off >>= 1) v += __shfl_down(v, off);
    if (t == 0)
      out[4 * N_TOK] = (float)NEXP * v * (1.f / (float)N_TOK) * (1.f / (float)N_TOK);
  }
}

extern "C" void kernel_launch(void* const* d_in, const int* in_sizes, int n_in,
                              void* d_out, int out_size, void* d_ws, size_t ws_size,
                              hipStream_t stream) {
  const float* x  = (const float*)d_in[0];
  const float* Wg = (const float*)d_in[1];
  float* out = (float*)d_out;

  const size_t need = (size_t)NBLK * NEXP * 2 * sizeof(float);  // 256 KB
  if (ws_size >= need) {
    float* cnt_p = (float*)d_ws;
    float* sp_p  = cnt_p + (size_t)NBLK * NEXP;
    router_kernel<true><<<dim3(NBLK), dim3(NTHR), 0, stream>>>(x, Wg, out, cnt_p, sp_p);
    aux_kernel<<<dim3(1), dim3(256), 0, stream>>>(cnt_p, sp_p, out, NBLK);
  } else {
    float* cnt_p = (float*)d_ws;           // [64]
    float* sp_p  = cnt_p + NEXP;           // [64]
    hipMemsetAsync(d_ws, 0, 2 * NEXP * sizeof(float), stream);
    router_kernel<false><<<dim3(NBLK), dim3(NTHR), 0, stream>>>(x, Wg, out, cnt_p, sp_p);
    aux_kernel<<<dim3(1), dim3(256), 0, stream>>>(cnt_p, sp_p, out, 1);
  }
}